// Round 5
// baseline (247.121 us; speedup 1.0000x reference)
//
#include <hip/hip_runtime.h>
#include <cstdint>
#include <cstddef>

// Problem constants
//   x[1024,256] f32, W1[1024,256] f32, b1[1024], W2[32896,1024] f32, b2[32896]
//   h = softplus(x@W1^T + b1)          [1024,1024]  (bf16 in ws)
//   elements = h@W2^T + b2             first TRI=32640 cols used
//   out[b,i,j] = elements[b, i(i-1)/2+j] for i>j; out[b,j,i] = -that; diag 0
#define TRI 32640
#define NPAD 32768          // N padded to 128 x 256-tiles (rows exist in W2)

using u32   = unsigned int;
using u16   = unsigned short;
using f32x4 = __attribute__((ext_vector_type(4))) float;
using u32x4 = __attribute__((ext_vector_type(4))) u32;
using bf16x8 = __attribute__((ext_vector_type(8))) short;

__device__ __forceinline__ void gload_lds16(const void* g, void* l) {
  // async global->LDS, 16B/lane; LDS dest = wave-uniform base + lane*16
  __builtin_amdgcn_global_load_lds(
      (const __attribute__((address_space(1))) void*)g,
      (__attribute__((address_space(3))) void*)l, 16, 0, 0);
}

__device__ __forceinline__ u32 pack2bf(float a, float b) {
  u32 ua = __builtin_bit_cast(u32, a);
  u32 ub = __builtin_bit_cast(u32, b);
  return (ub & 0xffff0000u) | (ua >> 16);
}

__device__ __forceinline__ u16 f2bf_rn(float f) {  // round-to-nearest-even
  u32 u = __builtin_bit_cast(u32, f);
  u += 0x7fffu + ((u >> 16) & 1u);
  return (u16)(u >> 16);
}

#define MEMFENCE asm volatile("" ::: "memory")

// ---------------------------------------------------------------------------
// K0 (fused): blocks 0-63   : h = softplus(x @ W1^T + b1), bf16 (m97-style)
//             blocks 64-1087: convert W2[0:NPAD,:] f32 -> bf16(rn) into ws
// ---------------------------------------------------------------------------
__global__ __launch_bounds__(256)
void k0_fused(const float* __restrict__ x, const float* __restrict__ W1,
              const float* __restrict__ b1, u16* __restrict__ h,
              const float* __restrict__ W2, u16* __restrict__ W2b)
{
  __shared__ float ldsA[128*32];
  __shared__ float ldsB[128*32];

  if (blockIdx.x >= 64) {
    const int g0 = (blockIdx.x - 64)*256 + threadIdx.x;
    const f32x4* src = (const f32x4*)W2;
    const int n4 = NPAD*1024/4;           // 8,388,608 (exact, 32 iters)
    for (int v = g0; v < n4; v += 1024*256) {
      f32x4 f = src[v];
      uint2 p;
      p.x = (u32)f2bf_rn(f.x) | ((u32)f2bf_rn(f.y) << 16);
      p.y = (u32)f2bf_rn(f.z) | ((u32)f2bf_rn(f.w) << 16);
      *(uint2*)(W2b + (size_t)v*4) = p;
    }
    return;
  }

  const int tid = threadIdx.x, lane = tid & 63, wave = tid >> 6;
  const int wm = wave >> 1, wn = wave & 1;
  const int brow = (blockIdx.x & 7) * 128, bcol = (blockIdx.x >> 3) * 128;

  const int s_row = wave*8 + (lane >> 3);
  const int s_col = (lane & 7) * 4;
  const float* gA = x  + (brow + s_row)*256 + s_col;
  const float* gB = W1 + (bcol + s_row)*256 + s_col;
  float* lA = &ldsA[wave*256];
  float* lB = &ldsB[wave*256];

  const int fr = lane & 15, fk = (lane >> 4) * 8;
  const float* rdA = &ldsA[(wm*64 + fr)*32 + fk];
  const float* rdB = &ldsB[(wn*64 + fr)*32 + fk];

  f32x4 acc[4][4] = {};
  for (int kt = 0; kt < 8; ++kt) {
    __syncthreads();
#pragma unroll
    for (int q = 0; q < 4; ++q) {
      gload_lds16(gA + q*32*256 + kt*32, lA + q*1024);
      gload_lds16(gB + q*32*256 + kt*32, lB + q*1024);
    }
    __syncthreads();
    bf16x8 af[4], bfv[4];
#pragma unroll
    for (int m = 0; m < 4; ++m) {
      f32x4 lo = *(const f32x4*)(rdA + m*512);
      f32x4 hi = *(const f32x4*)(rdA + m*512 + 4);
      u32x4 p = { pack2bf(lo.x,lo.y), pack2bf(lo.z,lo.w),
                  pack2bf(hi.x,hi.y), pack2bf(hi.z,hi.w) };
      af[m] = __builtin_bit_cast(bf16x8, p);
    }
#pragma unroll
    for (int n = 0; n < 4; ++n) {
      f32x4 lo = *(const f32x4*)(rdB + n*512);
      f32x4 hi = *(const f32x4*)(rdB + n*512 + 4);
      u32x4 p = { pack2bf(lo.x,lo.y), pack2bf(lo.z,lo.w),
                  pack2bf(hi.x,hi.y), pack2bf(hi.z,hi.w) };
      bfv[n] = __builtin_bit_cast(bf16x8, p);
    }
#pragma unroll
    for (int m = 0; m < 4; ++m)
#pragma unroll
      for (int n = 0; n < 4; ++n)
        acc[m][n] = __builtin_amdgcn_mfma_f32_16x16x32_bf16(af[m], bfv[n], acc[m][n], 0,0,0);
  }
#pragma unroll
  for (int n = 0; n < 4; ++n) {
    const int col = bcol + wn*64 + n*16 + fr;
    const float bias = b1[col];
#pragma unroll
    for (int m = 0; m < 4; ++m) {
      const int row0 = brow + wm*64 + m*16 + (lane >> 4)*4;
#pragma unroll
      for (int r = 0; r < 4; ++r) {
        float z = acc[m][n][r] + bias;
        float sp = fmaxf(z, 0.f) + log1pf(expf(-fabsf(z)));
        h[(row0 + r)*1024 + col] = f2bf_rn(sp);
      }
    }
  }
}

// ---------------------------------------------------------------------------
// K2: elements = h @ W2b^T (+b2), forward-half scatter.
// 256x256 tile, BK=32, 8 waves (2M x 4N), 3-SLOT deep pipeline (96 KB LDS):
// at K-tile t, stage ALL of tile t+2 into slot (t+2)%3 -> issue-to-deadline
// = 2 K-tile periods >> HBM latency. ONE barrier + ONE vmcnt(4) per K-tile
// (slot (t+2)%3 holds tile t-1, fully consumed before the barrier at end of
// t-1, so DMA can land any time up to the vmcnt at end of t+1; per-wave
// vmcnt(4) BEFORE the barrier ensures all waves' tile-t+1 data is in LDS
// before anyone reads it). No intra-tile lockstep -> waves skew -> ds_read
// and MFMA pipes overlap across waves.
//
// LDS unit-swizzle (r3-proven, 0 conflicts): 64B rows, 4x16B units,
// unit ^= (row>>1)&3, applied both sides (inverse-permuted global source for
// the linear gload_lds dest + swizzled ds_read address).
// ---------------------------------------------------------------------------
#define BOFF 49152u          // byte offset of B region (3 x 16KB A slots first)

__global__ __launch_bounds__(512)
void k2_gemm_deep(const u16* __restrict__ h, const u16* __restrict__ W2b,
                  const float* __restrict__ b2, float* __restrict__ out)
{
  __shared__ u16 lds[49152];      // 96 KB: A slots 0..2 @0/16/32K, B @48/64/80K

  const int tid = threadIdx.x, lane = tid & 63, wv = tid >> 6;   // wv 0..7
  const int wr = wv >> 2, wc = wv & 3;                           // 2M x 4N

  // XCD-bijective swizzle (512 % 8 == 0): 4 m-tiles sharing a B-panel are
  // consecutive logical blocks -> same XCD chunk.
  const int L = (blockIdx.x & 7) * 64 + (blockIdx.x >> 3);
  const int brow = (L & 3) * 256;          // batch tile
  const int t0   = (L >> 2) * 256;         // t tile

  // ---- staging constants ----
  const int srow0 = wv*32 + (lane >> 2);            // q=0 row
  const int sunit = (lane & 3) ^ ((lane >> 3) & 3); // inverse-swizzled unit
  const u16* sA0 = h   + (size_t)(brow + srow0     )*1024 + sunit*8;
  const u16* sA1 = h   + (size_t)(brow + srow0 + 16)*1024 + sunit*8;
  const u16* sB0 = W2b + (size_t)(t0   + srow0     )*1024 + sunit*8;
  const u16* sB1 = W2b + (size_t)(t0   + srow0 + 16)*1024 + sunit*8;
  const u32 dst0 = (u32)wv*2048u;                   // + lane*16 by HW
  const u32 dst1 = dst0 + 1024u;

  // ---- ds_read offsets (bytes within a slot) ----
  const int fr = lane & 15, lg = lane >> 4;
  const u32 uoff = (u32)((lg ^ ((fr >> 1) & 3)) * 16);
  u32 aoff[8], boff[4];
#pragma unroll
  for (int m = 0; m < 8; ++m)
    aoff[m] = (u32)((wr*128 + m*16 + fr) * 64) + uoff;
#pragma unroll
  for (int n = 0; n < 4; ++n)
    boff[n] = (u32)((wc*64 + n*16 + fr) * 64) + uoff;

  char* ldsb = (char*)lds;
  f32x4 acc[8][4] = {};

  // ---- prologue: stage tiles 0,1 (A+B each); wait tile 0 (oldest 4) ----
  gload_lds16(sA0,      ldsb + dst0);
  gload_lds16(sA1,      ldsb + dst1);
  gload_lds16(sB0,      ldsb + BOFF + dst0);
  gload_lds16(sB1,      ldsb + BOFF + dst1);
  gload_lds16(sA0 + 32, ldsb + 16384u + dst0);
  gload_lds16(sA1 + 32, ldsb + 16384u + dst1);
  gload_lds16(sB0 + 32, ldsb + BOFF + 16384u + dst0);
  gload_lds16(sB1 + 32, ldsb + BOFF + 16384u + dst1);
  asm volatile("s_waitcnt vmcnt(4)" ::: "memory");
  MEMFENCE; __builtin_amdgcn_s_barrier(); MEMFENCE;

  u32 rb = 0u, wb = 32768u;       // read slot byte, write slot byte ((t+2)%3)
#pragma unroll 2
  for (int t = 0; t < 32; ++t) {
    const int kb = ((t+2 < 32) ? t+2 : 31) * 32;   // clamped; dup writes benign

    // j0 reads: A fragments m=0..3 + all B fragments
    bf16x8 a0 = *(const bf16x8*)(ldsb + rb + aoff[0]);
    bf16x8 a1 = *(const bf16x8*)(ldsb + rb + aoff[1]);
    bf16x8 a2 = *(const bf16x8*)(ldsb + rb + aoff[2]);
    bf16x8 a3 = *(const bf16x8*)(ldsb + rb + aoff[3]);
    bf16x8 b0 = *(const bf16x8*)(ldsb + BOFF + rb + boff[0]);
    bf16x8 b1 = *(const bf16x8*)(ldsb + BOFF + rb + boff[1]);
    bf16x8 b2v = *(const bf16x8*)(ldsb + BOFF + rb + boff[2]);
    bf16x8 b3 = *(const bf16x8*)(ldsb + BOFF + rb + boff[3]);

    // stage tile t+2 into slot (t+2)%3 (holds t-1: consumed before last barrier)
    gload_lds16(sA0 + kb, ldsb + wb + dst0);
    gload_lds16(sA1 + kb, ldsb + wb + dst1);
    gload_lds16(sB0 + kb, ldsb + BOFF + wb + dst0);
    gload_lds16(sB1 + kb, ldsb + BOFF + wb + dst1);

    asm volatile("s_waitcnt lgkmcnt(0)" ::: "memory");
    __builtin_amdgcn_sched_barrier(0);
    __builtin_amdgcn_s_setprio(1);
#pragma unroll
    for (int m = 0; m < 4; ++m) {
      const bf16x8 am = (m==0)?a0:(m==1)?a1:(m==2)?a2:a3;
      acc[m][0] = __builtin_amdgcn_mfma_f32_16x16x32_bf16(am, b0,  acc[m][0], 0,0,0);
      acc[m][1] = __builtin_amdgcn_mfma_f32_16x16x32_bf16(am, b1,  acc[m][1], 0,0,0);
      acc[m][2] = __builtin_amdgcn_mfma_f32_16x16x32_bf16(am, b2v, acc[m][2], 0,0,0);
      acc[m][3] = __builtin_amdgcn_mfma_f32_16x16x32_bf16(am, b3,  acc[m][3], 0,0,0);
    }
    __builtin_amdgcn_s_setprio(0);

    // j1 reads: A fragments m=4..7 (B regs stay live)
    bf16x8 a4 = *(const bf16x8*)(ldsb + rb + aoff[4]);
    bf16x8 a5 = *(const bf16x8*)(ldsb + rb + aoff[5]);
    bf16x8 a6 = *(const bf16x8*)(ldsb + rb + aoff[6]);
    bf16x8 a7 = *(const bf16x8*)(ldsb + rb + aoff[7]);
    asm volatile("s_waitcnt lgkmcnt(0)" ::: "memory");
    __builtin_amdgcn_sched_barrier(0);
    __builtin_amdgcn_s_setprio(1);
#pragma unroll
    for (int m = 4; m < 8; ++m) {
      const bf16x8 am = (m==4)?a4:(m==5)?a5:(m==6)?a6:a7;
      acc[m][0] = __builtin_amdgcn_mfma_f32_16x16x32_bf16(am, b0,  acc[m][0], 0,0,0);
      acc[m][1] = __builtin_amdgcn_mfma_f32_16x16x32_bf16(am, b1,  acc[m][1], 0,0,0);
      acc[m][2] = __builtin_amdgcn_mfma_f32_16x16x32_bf16(am, b2v, acc[m][2], 0,0,0);
      acc[m][3] = __builtin_amdgcn_mfma_f32_16x16x32_bf16(am, b3,  acc[m][3], 0,0,0);
    }
    __builtin_amdgcn_s_setprio(0);

    // tile t+1 (oldest 4 outstanding) must be in LDS before anyone reads it
    asm volatile("s_waitcnt vmcnt(4)" ::: "memory");
    MEMFENCE; __builtin_amdgcn_s_barrier(); MEMFENCE;

    rb = (rb == 32768u) ? 0u : rb + 16384u;
    wb = (wb == 32768u) ? 0u : wb + 16384u;
  }
  asm volatile("s_waitcnt vmcnt(0)" ::: "memory");   // drain tail DMAs

  // ---- epilogue: t -> (i,j) strict-lower scatter, forward half only ----
#pragma unroll
  for (int n = 0; n < 4; ++n) {
    const int t = t0 + wc*64 + n*16 + fr;
    if (t >= TRI) continue;
    const float bias = b2[t];
    int i = (int)((1.0f + sqrtf((float)(8*t + 1))) * 0.5f);
    while (i*(i+1)/2 <= t) ++i;
    while (i*(i-1)/2 > t) --i;
    const int j = t - i*(i-1)/2;
    const int ijbase = i*256 + j;
#pragma unroll
    for (int m = 0; m < 8; ++m) {
      const int row0 = brow + wr*128 + m*16 + (lane >> 4)*4;
#pragma unroll
      for (int r = 0; r < 4; ++r)
        out[(size_t)(row0 + r)*65536 + ijbase] = acc[m][n][r] + bias;
    }
  }
}

// ---------------------------------------------------------------------------
// Fallback path (ws too small): round-1 kernels, proven correct.
// ---------------------------------------------------------------------------
__global__ __launch_bounds__(256)
void k1_gemm_softplus(const float* __restrict__ x, const float* __restrict__ W1,
                      const float* __restrict__ b1, u16* __restrict__ h)
{
  __shared__ float ldsA[128*32];
  __shared__ float ldsB[128*32];
  const int tid = threadIdx.x, lane = tid & 63, wave = tid >> 6;
  const int wm = wave >> 1, wn = wave & 1;
  const int brow = (blockIdx.x & 7) * 128, bcol = (blockIdx.x >> 3) * 128;
  const int s_row = wave*8 + (lane >> 3);
  const int s_col = (lane & 7) * 4;
  const float* gA = x  + (brow + s_row)*256 + s_col;
  const float* gB = W1 + (bcol + s_row)*256 + s_col;
  float* lA = &ldsA[wave*256];
  float* lB = &ldsB[wave*256];
  const int fr = lane & 15, fk = (lane >> 4) * 8;
  const float* rdA = &ldsA[(wm*64 + fr)*32 + fk];
  const float* rdB = &ldsB[(wn*64 + fr)*32 + fk];
  f32x4 acc[4][4] = {};
  for (int kt = 0; kt < 8; ++kt) {
    __syncthreads();
#pragma unroll
    for (int q = 0; q < 4; ++q) {
      gload_lds16(gA + q*32*256 + kt*32, lA + q*1024);
      gload_lds16(gB + q*32*256 + kt*32, lB + q*1024);
    }
    __syncthreads();
    bf16x8 af[4], bfv[4];
#pragma unroll
    for (int m = 0; m < 4; ++m) {
      f32x4 lo = *(const f32x4*)(rdA + m*512);
      f32x4 hi = *(const f32x4*)(rdA + m*512 + 4);
      u32x4 p = { pack2bf(lo.x,lo.y), pack2bf(lo.z,lo.w),
                  pack2bf(hi.x,hi.y), pack2bf(hi.z,hi.w) };
      af[m] = __builtin_bit_cast(bf16x8, p);
    }
#pragma unroll
    for (int n = 0; n < 4; ++n) {
      f32x4 lo = *(const f32x4*)(rdB + n*512);
      f32x4 hi = *(const f32x4*)(rdB + n*512 + 4);
      u32x4 p = { pack2bf(lo.x,lo.y), pack2bf(lo.z,lo.w),
                  pack2bf(hi.x,hi.y), pack2bf(hi.z,hi.w) };
      bfv[n] = __builtin_bit_cast(bf16x8, p);
    }
#pragma unroll
    for (int m = 0; m < 4; ++m)
#pragma unroll
      for (int n = 0; n < 4; ++n)
        acc[m][n] = __builtin_amdgcn_mfma_f32_16x16x32_bf16(af[m], bfv[n], acc[m][n], 0,0,0);
  }
#pragma unroll
  for (int n = 0; n < 4; ++n) {
    const int col = bcol + wn*64 + n*16 + fr;
    const float bias = b1[col];
#pragma unroll
    for (int m = 0; m < 4; ++m) {
      const int row0 = brow + wm*64 + m*16 + (lane >> 4)*4;
#pragma unroll
      for (int r = 0; r < 4; ++r) {
        float z = acc[m][n][r] + bias;
        float sp = fmaxf(z, 0.f) + log1pf(expf(-fabsf(z)));
        h[(row0 + r)*1024 + col] = f2bf_rn(sp);
      }
    }
  }
}

__global__ __launch_bounds__(256)
void k2_gemm_scatter(const u16* __restrict__ h, const float* __restrict__ W2,
                     const float* __restrict__ b2, float* __restrict__ out)
{
  __shared__ u16   ldsA[128*32];
  __shared__ float ldsB[128*32];
  const int tid = threadIdx.x, lane = tid & 63, wave = tid >> 6;
  const int wm = wave >> 1, wn = wave & 1;
  const int bid = blockIdx.x;
  const int L  = (bid & 7) * 255 + (bid >> 3);
  const int t0 = (L >> 3) * 128;
  const int brow = (L & 7) * 128;
  const int a_row = wave*16 + (lane >> 2);
  const int a_col = (lane & 3) * 8;
  const u16* gA = h + (brow + a_row)*1024 + a_col;
  u16* lA = &ldsA[wave*512];
  const int b_row = wave*8 + (lane >> 3);
  const int b_col = (lane & 7) * 4;
  const float* gB = W2 + (size_t)(t0 + b_row)*1024 + b_col;
  float* lB = &ldsB[wave*256];
  const int fr = lane & 15, fk = (lane >> 4) * 8;
  const u16*   rdA = &ldsA[(wm*64 + fr)*32 + fk];
  const float* rdB = &ldsB[(wn*64 + fr)*32 + fk];
  f32x4 acc[4][4] = {};
  for (int kt = 0; kt < 32; ++kt) {
    __syncthreads();
#pragma unroll
    for (int q = 0; q < 2; ++q)
      gload_lds16(gA + q*64*1024 + kt*32, lA + q*2048);
#pragma unroll
    for (int q = 0; q < 4; ++q)
      gload_lds16(gB + q*32*1024 + kt*32, lB + q*1024);
    __syncthreads();
    bf16x8 af[4];
#pragma unroll
    for (int m = 0; m < 4; ++m)
      af[m] = *(const bf16x8*)(rdA + m*512);
#pragma unroll
    for (int n = 0; n < 4; ++n) {
      f32x4 lo = *(const f32x4*)(rdB + n*512);
      f32x4 hi = *(const f32x4*)(rdB + n*512 + 4);
      u32x4 p = { pack2bf(lo.x,lo.y), pack2bf(lo.z,lo.w),
                  pack2bf(hi.x,hi.y), pack2bf(hi.z,hi.w) };
      bf16x8 bfr = __builtin_bit_cast(bf16x8, p);
#pragma unroll
      for (int m = 0; m < 4; ++m)
        acc[m][n] = __builtin_amdgcn_mfma_f32_16x16x32_bf16(af[m], bfr, acc[m][n], 0,0,0);
    }
  }
#pragma unroll
  for (int n = 0; n < 4; ++n) {
    const int t = t0 + wn*64 + n*16 + fr;
    const float bias = b2[t];
    int i = (int)((1.0f + sqrtf((float)(8*t + 1))) * 0.5f);
    while (i*(i+1)/2 <= t) ++i;
    while (i*(i-1)/2 > t) --i;
    const int j = t - i*(i-1)/2;
    const int ijbase = i*256 + j;
#pragma unroll
    for (int m = 0; m < 4; ++m) {
      const int row0 = brow + wm*64 + m*16 + (lane >> 4)*4;
#pragma unroll
      for (int r = 0; r < 4; ++r)
        out[(size_t)(row0 + r)*65536 + ijbase] = acc[m][n][r] + bias;
    }
  }
}

// ---------------------------------------------------------------------------
// K3: antisymmetrize. Read lower 64x64 tiles, write -tile^T to upper.
// ---------------------------------------------------------------------------
__global__ __launch_bounds__(256)
void k3_mirror(float* __restrict__ out)
{
  __shared__ float tile[64][65];
  const int b = blockIdx.y;
  const int k = blockIdx.x;
  int ib, jb;
  if (k < 4) { ib = k; jb = k; }
  else {
    const int pi[6] = {1,2,2,3,3,3};
    const int pj[6] = {0,0,1,0,1,2};
    ib = pi[k-4]; jb = pj[k-4];
  }
  const int i0 = ib*64, j0 = jb*64;
  float* A = out + (size_t)b*65536;
  const int tid = threadIdx.x;
  const int r = tid >> 2, c0 = (tid & 3) * 16;
#pragma unroll
  for (int q = 0; q < 4; ++q) {
    const float4 v = *(const float4*)(A + (i0 + r)*256 + j0 + c0 + q*4);
    tile[r][c0+q*4+0] = v.x;
    tile[r][c0+q*4+1] = v.y;
    tile[r][c0+q*4+2] = v.z;
    tile[r][c0+q*4+3] = v.w;
  }
  __syncthreads();
  if (ib != jb) {
#pragma unroll
    for (int q = 0; q < 4; ++q) {
      const int c = c0 + q*4;
      float4 v;
      v.x = -tile[c+0][r]; v.y = -tile[c+1][r];
      v.z = -tile[c+2][r]; v.w = -tile[c+3][r];
      *(float4*)(A + (j0 + r)*256 + i0 + c) = v;
    }
  } else {
#pragma unroll
    for (int q = 0; q < 4; ++q) {
      const int cb = c0 + q*4;
      float4 v;
#pragma unroll
      for (int e = 0; e < 4; ++e) {
        const int c = cb + e;
        float val = (c < r) ? tile[r][c] : ((c == r) ? 0.f : -tile[c][r]);
        ((float*)&v)[e] = val;
      }
      *(float4*)(A + (i0 + r)*256 + j0 + cb) = v;
    }
  }
}

// ---------------------------------------------------------------------------
extern "C" void kernel_launch(void* const* d_in, const int* in_sizes, int n_in,
                              void* d_out, int out_size, void* d_ws, size_t ws_size,
                              hipStream_t stream) {
  const float* x  = (const float*)d_in[0];
  const float* W1 = (const float*)d_in[1];
  const float* b1 = (const float*)d_in[2];
  const float* W2 = (const float*)d_in[3];
  const float* b2 = (const float*)d_in[4];
  float* out = (float*)d_out;
  u16* h = (u16*)d_ws;                               // 2 MB

  const size_t need = 2u*1024*1024 + (size_t)NPAD*1024*2;   // h + W2 bf16 (padded)
  if (ws_size >= need) {
    u16* W2b = (u16*)((char*)d_ws + 2u*1024*1024);
    k0_fused        <<<dim3(64 + 1024), dim3(256), 0, stream>>>(x, W1, b1, h, W2, W2b);
    k2_gemm_deep    <<<dim3(512),       dim3(512), 0, stream>>>(h, W2b, b2, out);
  } else {
    k1_gemm_softplus<<<dim3(64),        dim3(256), 0, stream>>>(x, W1, b1, h);
    k2_gemm_scatter <<<dim3(2040),      dim3(256), 0, stream>>>(h, W2, b2, out);
  }
  k3_mirror         <<<dim3(10, 1024),  dim3(256), 0, stream>>>(out);
}